// Round 3
// baseline (157.058 us; speedup 1.0000x reference)
//
#include <hip/hip_runtime.h>
#include <hip/hip_bf16.h>

// Problem constants
#define B_  4096
#define T_  80
#define E_  100
#define U_  64
#define G_  256    // 4*U
#define V_  10000

#define S_H  72    // hbuf row stride (bf16 elems); b128 reads land 8 lanes per 4-bank group (minimum for b128) -> conflict-minimal
#define TS   81    // token LDS row stride (ints); odd stride spreads 16 rows over 16 banks

typedef __attribute__((ext_vector_type(8))) __bf16 bf16x8;
typedef __attribute__((ext_vector_type(4))) __bf16 bf16x4;
typedef __attribute__((ext_vector_type(4))) float  floatx4;

__device__ __forceinline__ float sigmoidf_(float x) {
    return __builtin_amdgcn_rcpf(1.f + __expf(-x));
}

__device__ __forceinline__ float tanhf_(float x) {
    // 1 - 2/(e^{2x}+1): monotone, saturates correctly, no NaN
    return fmaf(-2.f, __builtin_amdgcn_rcpf(__expf(2.f * x) + 1.f), 1.f);
}

// Block-wide barrier WITHOUT the vmcnt(0) drain __syncthreads() forces.
// Only LDS traffic (h writes) must be visible across waves per step; the
// emb gather loads are thread-private VGPR fills tracked by the compiler's
// own counted s_waitcnt vmcnt(N) at first use.
__device__ __forceinline__ void block_sync_lgkm() {
    asm volatile("s_waitcnt lgkmcnt(0)\n\ts_barrier" ::: "memory");
}

__device__ __forceinline__ bf16x8 cvt8(const float4& a, const float4& b) {
    bf16x8 r;
    r[0] = (__bf16)a.x; r[1] = (__bf16)a.y; r[2] = (__bf16)a.z; r[3] = (__bf16)a.w;
    r[4] = (__bf16)b.x; r[5] = (__bf16)b.y; r[6] = (__bf16)b.z; r[7] = (__bf16)b.w;
    return r;
}

// ---------------------------------------------------------------------------
// Single fused kernel. Recurrence via TRANSPOSED MFMA: z^T = k1^T x^T + r1^T h^T + b.
// 256 blocks x 256 threads (4 waves). Block = 16 batch rows; wave w owns
// units [w*16, w*16+16) -> 4 gate-col tiles.
//
// Per-step schedule (the R2->R3 fix): the x-projection for step t+1 is
// SPLIT and tucked into this step's latency shadows:
//   1. issue emb gathers for t+2          (vmem queue, fire-and-forget)
//   2. issue ds_read of h_{t-1}           (~120 cy latency)
//   3. xcvt: float->bf16 frags for x_{t+1} (VALU, overlaps ds_read latency)
//   4. acc MFMAs (z_t)                    (matrix pipe, issued first)
//   5. x MFMAs (z_x for t+1)              (drain on matrix pipe DURING gates)
//   6. gates (trans/VALU pipe)            (overlaps step 5's dependent chain)
//   7. write h_t, lgkmcnt(0)+s_barrier    (loads stay in flight)
// In R2 steps 3+5 ran AFTER 6, appending ~810 cy of cvt+dependent-MFMA
// latency to the serial chain with nothing to overlap.
//
// MFMA accumulation order (bias -> x0..x3 -> h0,h1) is byte-identical to R2.
// ---------------------------------------------------------------------------
__global__ __launch_bounds__(256, 1) void lstm_kernel(const int*   __restrict__ tokens,
                                                      const float* __restrict__ emb,
                                                      const float* __restrict__ k1,
                                                      const float* __restrict__ r1,
                                                      const float* __restrict__ b1,
                                                      const float* __restrict__ Wd,
                                                      const float* __restrict__ bd,
                                                      float* __restrict__ out) {
    __shared__ int    tokLDS[16 * TS];       // 5.18 KB
    __shared__ __bf16 hbuf[2][16 * S_H];     // 4.6 KB

    const int tid  = threadIdx.x;
    const int lane = tid & 63;
    const int w    = tid >> 6;               // unit block [w*16, w*16+16)
    const int n    = lane & 15;              // batch row (N-operand of MFMA)
    const int kg   = lane >> 4;              // 0..3
    const int bb   = blockIdx.x * 16;

    for (int i = tid; i < 16 * T_; i += 256)
        tokLDS[(i / T_) * TS + (i % T_)] = tokens[bb * T_ + i];
    for (int i = tid; i < 2 * 16 * S_H; i += 256) (&hbuf[0][0])[i] = (__bf16)0.f;

    // A-fragments = r1^T (static): tile ct covers gate-cols ct*64 + w*16 + m,
    // A[m][k] = r1[k][ct*64 + w*16 + m]; lane holds m = n, k = kc*32 + kg*8 + jj
    bf16x8 afr[4][2];
#pragma unroll
    for (int ct = 0; ct < 4; ++ct)
#pragma unroll
        for (int kc = 0; kc < 2; ++kc) {
            bf16x8 s;
#pragma unroll
            for (int jj = 0; jj < 8; ++jj)
                s[jj] = (__bf16)r1[(kc * 32 + kg * 8 + jj) * G_ + ct * 64 + w * 16 + n];
            afr[ct][kc] = s;
        }

    // A-fragments = k1^T (static), K padded 100 -> 128 with zeros
    bf16x8 kfr[4][4];
#pragma unroll
    for (int ct = 0; ct < 4; ++ct)
#pragma unroll
        for (int kc = 0; kc < 4; ++kc) {
            bf16x8 s;
#pragma unroll
            for (int jj = 0; jj < 8; ++jj) {
                int k = kc * 32 + kg * 8 + jj;
                s[jj] = (k < E_) ? (__bf16)k1[k * G_ + ct * 64 + w * 16 + n]
                                 : (__bf16)0.f;
            }
            kfr[ct][kc] = s;
        }

    // bias in C layout: row of C = gate col = ct*64 + w*16 + kg*4 + r
    floatx4 bias[4];
#pragma unroll
    for (int ct = 0; ct < 4; ++ct)
#pragma unroll
        for (int r = 0; r < 4; ++r)
            bias[ct][r] = b1[ct * 64 + w * 16 + kg * 4 + r];

    // cell state: 4 cells/lane: (row n, unit w*16 + 4*kg + r)
    float c[4] = {0.f, 0.f, 0.f, 0.f};

    __syncthreads();                         // tokens + zeroed hbuf visible (once)

    const int trow = n * TS;

    // ---- emb staging: lane (n,kg) supplies B[k][n] = emb[tok_n][k],
    //      k = kc*32 + kg*8 + jj. 7 x dwordx4 per lane (kc=3 only kg==0 valid).
    auto ldstage = [&](int tk, float4* st) {
        const float* base = emb + (long)tk * E_;
#pragma unroll
        for (int kc = 0; kc < 3; ++kc) {
            st[kc * 2]     = *(const float4*)(base + kc * 32 + kg * 8);
            st[kc * 2 + 1] = *(const float4*)(base + kc * 32 + kg * 8 + 4);
        }
        st[6] = *(const float4*)(base + 96);  // uniform issue; masked in xcvt
    };

    // ---- x-projection, phase 1: float->bf16 fragment build (pure VALU)
    auto xcvt = [&](const float4* st, bf16x8* xf) {
        xf[0] = cvt8(st[0], st[1]);
        xf[1] = cvt8(st[2], st[3]);
        xf[2] = cvt8(st[4], st[5]);
        float4 e3 = st[6];
        if (kg) { e3.x = 0.f; e3.y = 0.f; e3.z = 0.f; e3.w = 0.f; }
        bf16x8 x3;
        x3[0] = (__bf16)e3.x; x3[1] = (__bf16)e3.y;
        x3[2] = (__bf16)e3.z; x3[3] = (__bf16)e3.w;
        x3[4] = (__bf16)0.f;  x3[5] = (__bf16)0.f;
        x3[6] = (__bf16)0.f;  x3[7] = (__bf16)0.f;
        xf[3] = x3;
    };

    // ---- x-projection, phase 2: xo[ct] = b + k1^T x^T  (16 MFMA, matrix pipe)
    auto xmfma = [&](const bf16x8* xf, floatx4* xo) {
#pragma unroll
        for (int ct = 0; ct < 4; ++ct) {
            floatx4 a = bias[ct];
            a = __builtin_amdgcn_mfma_f32_16x16x32_bf16(kfr[ct][0], xf[0], a, 0, 0, 0);
            a = __builtin_amdgcn_mfma_f32_16x16x32_bf16(kfr[ct][1], xf[1], a, 0, 0, 0);
            a = __builtin_amdgcn_mfma_f32_16x16x32_bf16(kfr[ct][2], xf[2], a, 0, 0, 0);
            a = __builtin_amdgcn_mfma_f32_16x16x32_bf16(kfr[ct][3], xf[3], a, 0, 0, 0);
            xo[ct] = a;
        }
    };

    // ---- prologue: fill the pipeline
    float4  stA[7], stB[7];
    bf16x8  xf[4];
    floatx4 xaccA[4], xaccB[4];

    ldstage(tokLDS[trow + 0], stA);          // token 0
    xcvt(stA, xf);
    xmfma(xf, xaccA);                        // z_x(t=0)
    ldstage(tokLDS[trow + 1], stB);          // token 1 -> consumed in step 0
    int tkA = tokLDS[trow + 2];              // loads issued at even steps (t+2)
    int tkB = tokLDS[trow + 3];              // loads issued at odd steps  (t+2)

    auto step = [&](int t, const __bf16* hbR, __bf16* hbW,
                    floatx4* xuse, floatx4* xbld,
                    float4* stuse, float4* stbld, int& tkpf) {
        // 1. issue emb loads for token t+2 (fire-and-forget; consumed next step)
        ldstage(tkpf, stbld);
        int tnext = t + 4; if (tnext > T_ - 1) tnext = T_ - 1;
        tkpf = tokLDS[trow + tnext];

        // 2. B-fragments = h^T_{t-1} (ds_read issue; ~120cy latency)
        bf16x8 b0  = *(const bf16x8*)(hbR + n * S_H + kg * 8);
        bf16x8 b1v = *(const bf16x8*)(hbR + n * S_H + 32 + kg * 8);

        // 3. x-frag cvts for t+1 (VALU; independent of b0/b1 -> fills ds_read shadow)
        xcvt(stuse, xf);

        // 4. z^T = z_x + r1^T h^T  (consumes b0/b1 after lgkm wait)
        floatx4 acc[4];
#pragma unroll
        for (int ct = 0; ct < 4; ++ct) {
            floatx4 a = xuse[ct];
            a = __builtin_amdgcn_mfma_f32_16x16x32_bf16(afr[ct][0], b0,  a, 0, 0, 0);
            a = __builtin_amdgcn_mfma_f32_16x16x32_bf16(afr[ct][1], b1v, a, 0, 0, 0);
            acc[ct] = a;
        }

        // 5. x-projection MFMAs for t+1: issued now, drain on the matrix pipe
        //    while step 6's transcendentals run on the VALU/trans pipe.
        xmfma(xf, xbld);

        // 6. gates: 4 dense cells/lane; acc[0]=i, acc[1]=f, acc[2]=g, acc[3]=o
        bf16x4 hv;
#pragma unroll
        for (int r = 0; r < 4; ++r) {
            float zi = acc[0][r], zf = acc[1][r], zg = acc[2][r], zo = acc[3][r];
            float cn = fmaf(sigmoidf_(zf), c[r], sigmoidf_(zi) * tanhf_(zg));
            float hn = sigmoidf_(zo) * tanhf_(cn);
            c[r] = cn;
            hv[r] = (__bf16)hn;
        }
        // 7. h_new: 4 consecutive units -> one b64 write
        *(bf16x4*)(hbW + n * S_H + w * 16 + kg * 4) = hv;

        block_sync_lgkm();                   // h_t visible; loads stay in flight
    };

    for (int t = 0; t < T_; t += 2) {
        step(t,     hbuf[1], hbuf[0], xaccA, xaccB, stB, stA, tkA);
        step(t + 1, hbuf[0], hbuf[1], xaccB, xaccA, stA, stB, tkB);
    }

    // out[b] = sigmoid(h_final[b] . Wd + bd); h_79 in hbuf[1]
    if (tid < 16) {
        const __bf16* hb = hbuf[1] + tid * S_H;
        float s = bd[0];
#pragma unroll
        for (int u = 0; u < U_; ++u) s = fmaf((float)hb[u], Wd[u], s);
        out[bb + tid] = sigmoidf_(s);
    }
}

// ---------------------------------------------------------------------------
extern "C" void kernel_launch(void* const* d_in, const int* in_sizes, int n_in,
                              void* d_out, int out_size, void* d_ws, size_t ws_size,
                              hipStream_t stream) {
    const int*   tokens = (const int*)  d_in[0];
    const float* emb    = (const float*)d_in[1];
    // d_in[2..4] = k0, r0, b0 : dead in the reference (cell0 state unused)
    const float* k1     = (const float*)d_in[5];
    const float* r1     = (const float*)d_in[6];
    const float* b1     = (const float*)d_in[7];
    const float* Wd     = (const float*)d_in[8];
    const float* bd     = (const float*)d_in[9];
    float*       out    = (float*)d_out;

    lstm_kernel<<<B_ / 16, 256, 0, stream>>>(tokens, emb, k1, r1, b1, Wd, bd, out);
}

// Round 4
// 148.017 us; speedup vs baseline: 1.0611x; 1.0611x over previous
//
#include <hip/hip_runtime.h>
#include <hip/hip_bf16.h>

// Problem constants
#define B_  4096
#define T_  80
#define E_  100
#define U_  64
#define G_  256    // 4*U
#define V_  10000

#define S_H  72    // hbuf row stride (bf16 elems), 144B rows (16B aligned)
#define AS   136   // embk A-tile LDS stride (bf16): 272B rows, 16B aligned, %8==0
#define KS   136   // embk k1-tile (transposed) LDS stride (bf16)
#define TS   81    // token LDS row stride (ints); odd stride spreads 16 rows over
                   // 16 banks (stride 80 put them on banks {0,16}: 8-way, 2.1M conflicts in R1)

typedef __attribute__((ext_vector_type(8))) __bf16 bf16x8;
typedef __attribute__((ext_vector_type(4))) __bf16 bf16x4;
typedef __attribute__((ext_vector_type(4))) float  floatx4;

__device__ __forceinline__ float sigmoidf_(float x) {
    return __builtin_amdgcn_rcpf(1.f + __expf(-x));
}

__device__ __forceinline__ float tanhf_(float x) {
    // 1 - 2/(e^{2x}+1): monotone, saturates correctly, no NaN
    return fmaf(-2.f, __builtin_amdgcn_rcpf(__expf(2.f * x) + 1.f), 1.f);
}

// Block-wide barrier WITHOUT the vmcnt(0) drain __syncthreads() forces.
// Only LDS traffic (h writes) must be visible across waves per step; the
// embk gather loads are thread-private VGPR fills tracked by the compiler's
// own counted s_waitcnt vmcnt(N) at first use. (Measured R0->R1: -483 cy/step.)
__device__ __forceinline__ void block_sync_lgkm() {
    asm volatile("s_waitcnt lgkmcnt(0)\n\ts_barrier" ::: "memory");
}

// ---------------------------------------------------------------------------
// Kernel A (MFMA): embk[v][g] = b1[g] + emb[v] . k1[:,g]
// R4 change: B-fragments (k1 columns) no longer come from 64 scalar strided
// global loads per lane (the R1 kernel's dominant cost). The k1 tile is
// staged TRANSPOSED through LDS: coalesced float4 row reads -> bf16 scatter
// writes -> each lane's fragment is one contiguous ds_read_b128.
// Same bf16 rounding, same MFMA order, same store mapping as R1 ->
// bit-identical embk output.
// ---------------------------------------------------------------------------
__global__ __launch_bounds__(256) void embk_kernel(const float* __restrict__ emb,
                                                   const float* __restrict__ k1,
                                                   const float* __restrict__ b1,
                                                   float* __restrict__ embk) {
    __shared__ __bf16 aLDS[64 * AS];         // 17.4 KB  (emb tile)
    __shared__ __bf16 kLDS[128 * KS];        // 34.8 KB  (k1 tile, [col][k] layout)

    const int tid  = threadIdx.x;
    const int lane = tid & 63;
    const int w    = tid >> 6;               // wave: owns cols n0 + [w*32, w*32+32)
    const int n    = lane & 15;
    const int kg   = lane >> 4;
    const int v0   = (blockIdx.x >> 1) * 64;
    const int n0   = (blockIdx.x & 1) * 128;
    const int nrows = min(64, V_ - v0);

    // epoch 1: zero aLDS (full) and the kLDS zero-pad region k in [100,128)
    for (int i = tid; i < 64 * AS / 8; i += 256) {
        bf16x8 z;
#pragma unroll
        for (int jj = 0; jj < 8; ++jj) z[jj] = (__bf16)0.f;
        *(bf16x8*)(aLDS + i * 8) = z;
    }
    for (int i = tid; i < 128 * 28; i += 256) {
        int c = i / 28, kk = 100 + (i - c * 28);
        kLDS[c * KS + kk] = (__bf16)0.f;
    }

    const float bv0 = b1[n0 + w * 32 + n];
    const float bv1 = b1[n0 + w * 32 + 16 + n];

    __syncthreads();                         // zeroing visible before fills

    // epoch 2a: emb tile -> aLDS (rows, bf16), coalesced float4 reads
    for (int i = tid; i < nrows * 25; i += 256) {
        int r = i / 25, q = i - r * 25;
        float4 ev = *(const float4*)(emb + (long)(v0 + r) * E_ + q * 4);
        bf16x4 bv; bv[0] = (__bf16)ev.x; bv[1] = (__bf16)ev.y;
                   bv[2] = (__bf16)ev.z; bv[3] = (__bf16)ev.w;
        *(bf16x4*)(aLDS + r * AS + q * 4) = bv;
    }
    // epoch 2b: k1 tile -> kLDS transposed: kLDS[c][k] = bf16(k1[k][n0+c]),
    // k < 100. Reads coalesced (float4 along k1 rows); writes are 4 scalar
    // ds_write_u16 at stride KS*2 (one-time cost, replaces 64 scalar global
    // loads per lane).
    for (int i = tid; i < 100 * 32; i += 256) {
        int k = i >> 5, cq = (i & 31) * 4;
        float4 kv = *(const float4*)(k1 + (long)k * G_ + n0 + cq);
        kLDS[(cq + 0) * KS + k] = (__bf16)kv.x;
        kLDS[(cq + 1) * KS + k] = (__bf16)kv.y;
        kLDS[(cq + 2) * KS + k] = (__bf16)kv.z;
        kLDS[(cq + 3) * KS + k] = (__bf16)kv.w;
    }
    __syncthreads();

    // B-fragments from kLDS: lane (n,kg), tile ct -> col = w*32 + ct*16 + n,
    // k = kc*32 + kg*8 + jj : one contiguous b128 per (ct,kc)
    bf16x8 bfr[2][4];
#pragma unroll
    for (int ct = 0; ct < 2; ++ct)
#pragma unroll
        for (int kc = 0; kc < 4; ++kc)
            bfr[ct][kc] = *(const bf16x8*)(kLDS + (w * 32 + ct * 16 + n) * KS
                                                + kc * 32 + kg * 8);

#pragma unroll
    for (int mt = 0; mt < 4; ++mt) {
        const __bf16* ab = aLDS + (mt * 16 + n) * AS + kg * 8;
        bf16x8 a0 = *(const bf16x8*)(ab + 0);
        bf16x8 a1 = *(const bf16x8*)(ab + 32);
        bf16x8 a2 = *(const bf16x8*)(ab + 64);
        bf16x8 a3 = *(const bf16x8*)(ab + 96);
#pragma unroll
        for (int ct = 0; ct < 2; ++ct) {
            float bv = ct ? bv1 : bv0;
            floatx4 acc = {bv, bv, bv, bv};
            acc = __builtin_amdgcn_mfma_f32_16x16x32_bf16(a0, bfr[ct][0], acc, 0, 0, 0);
            acc = __builtin_amdgcn_mfma_f32_16x16x32_bf16(a1, bfr[ct][1], acc, 0, 0, 0);
            acc = __builtin_amdgcn_mfma_f32_16x16x32_bf16(a2, bfr[ct][2], acc, 0, 0, 0);
            acc = __builtin_amdgcn_mfma_f32_16x16x32_bf16(a3, bfr[ct][3], acc, 0, 0, 0);
#pragma unroll
            for (int r = 0; r < 4; ++r) {
                int v = v0 + mt * 16 + kg * 4 + r;
                if (v < V_) embk[(long)v * G_ + n0 + w * 32 + ct * 16 + n] = acc[r];
            }
        }
    }
}

// ---------------------------------------------------------------------------
// Kernel B: recurrence via TRANSPOSED MFMA: z^T = r1^T @ h^T.  (R1-exact
// revert, measured 69.6 us; only change: tokLDS stride 80 -> TS=81.)
// 256 blocks x 256 threads (4 waves = 1/SIMD). Block = 16 batch rows; wave w
// owns units [w*16, w*16+16) -> 4 gate-col tiles. C-init = xk float4 gathers
// from embk, prefetched TWO steps ahead; lgkm-only barrier keeps them in
// flight across steps. 4 fully-dense cells/lane, one b64 h-write, ONE
// barrier/step.
// ---------------------------------------------------------------------------
__global__ __launch_bounds__(256) void lstm_kernel(const int*   __restrict__ tokens,
                                                   const float* __restrict__ embk,
                                                   const float* __restrict__ r1,
                                                   const float* __restrict__ Wd,
                                                   const float* __restrict__ bd,
                                                   float* __restrict__ out) {
    __shared__ int    tokLDS[16 * TS];       // 5.18 KB
    __shared__ __bf16 hbuf[2][16 * S_H];     // 4.6 KB

    const int tid  = threadIdx.x;
    const int lane = tid & 63;
    const int w    = tid >> 6;               // unit block [w*16, w*16+16)
    const int n    = lane & 15;              // batch row (N-operand of MFMA)
    const int kg   = lane >> 4;              // 0..3
    const int bb   = blockIdx.x * 16;

    for (int i = tid; i < 16 * T_; i += 256)
        tokLDS[(i / T_) * TS + (i % T_)] = tokens[bb * T_ + i];
    for (int i = tid; i < 2 * 16 * S_H; i += 256) (&hbuf[0][0])[i] = (__bf16)0.f;

    // A-fragments = r1^T (static): tile ct covers gate-cols ct*64 + w*16 + m,
    // A[m][k] = r1[k][ct*64 + w*16 + m]; lane holds m = n, k = kc*32 + kg*8 + jj
    bf16x8 afr[4][2];
#pragma unroll
    for (int ct = 0; ct < 4; ++ct)
#pragma unroll
        for (int kc = 0; kc < 2; ++kc) {
            bf16x8 s;
#pragma unroll
            for (int jj = 0; jj < 8; ++jj)
                s[jj] = (__bf16)r1[(kc * 32 + kg * 8 + jj) * G_ + ct * 64 + w * 16 + n];
            afr[ct][kc] = s;
        }

    // cell state: 4 cells/lane: (row n, unit w*16 + 4*kg + r)
    float c[4] = {0.f, 0.f, 0.f, 0.f};

    __syncthreads();                         // tokens + zeroed hbuf visible

    // xk prefetch, 2 steps deep: xkb[s][ct] = embk[tok[n][s]][ct*64 + w*16 + 4kg .. +3]
    floatx4 xkb[2][4];
#pragma unroll
    for (int s = 0; s < 2; ++s) {
        const float* base = embk + (long)tokLDS[n * TS + s] * G_ + w * 16 + kg * 4;
#pragma unroll
        for (int ct = 0; ct < 4; ++ct)
            xkb[s][ct] = *(const floatx4*)(base + ct * 64);
    }

    auto step = [&](int t, int sel) {        // sel = t & 1 (constant at call site)
        // B-fragments = h^T_{t-1}: B[k][n] = h[n][k]; lane reads row n,
        // units kg*8..kg*8+7 (b0) and 32+kg*8..+7 (b1)
        const __bf16* hb = hbuf[sel ^ 1];
        bf16x8 b0 = *(const bf16x8*)(hb + n * S_H + kg * 8);
        bf16x8 b1 = *(const bf16x8*)(hb + n * S_H + 32 + kg * 8);

        // z^T tiles: acc[ct] = r1^T @ h^T + xk  (C-init = prefetched xk)
        floatx4 acc[4];
#pragma unroll
        for (int ct = 0; ct < 4; ++ct) {
            floatx4 a = xkb[sel][ct];
            a = __builtin_amdgcn_mfma_f32_16x16x32_bf16(afr[ct][0], b0, a, 0, 0, 0);
            a = __builtin_amdgcn_mfma_f32_16x16x32_bf16(afr[ct][1], b1, a, 0, 0, 0);
            acc[ct] = a;
        }

        // prefetch xk for t+2 into the slot just consumed (2-step window)
        if (t + 2 < T_) {
            const float* base = embk + (long)tokLDS[n * TS + t + 2] * G_ + w * 16 + kg * 4;
#pragma unroll
            for (int ct = 0; ct < 4; ++ct)
                xkb[sel][ct] = *(const floatx4*)(base + ct * 64);
        }

        // gates: 4 dense cells/lane; acc[0]=i, acc[1]=f, acc[2]=g, acc[3]=o
        bf16x4 hv;
#pragma unroll
        for (int r = 0; r < 4; ++r) {
            float zi = acc[0][r], zf = acc[1][r], zg = acc[2][r], zo = acc[3][r];
            float cn = fmaf(sigmoidf_(zf), c[r], sigmoidf_(zi) * tanhf_(zg));
            float hn = sigmoidf_(zo) * tanhf_(cn);
            c[r] = cn;
            hv[r] = (__bf16)hn;
        }
        // h_new: 4 consecutive units -> one b64 write
        *(bf16x4*)(&hbuf[sel][0] + n * S_H + w * 16 + kg * 4) = hv;

        block_sync_lgkm();                   // h_t visible; gathers stay in flight
    };

    for (int t = 0; t < T_; t += 2) {
        step(t,     0);
        step(t + 1, 1);
    }

    // out[b] = sigmoid(h_final[b] . Wd + bd); h_79 in hbuf[1]
    if (tid < 16) {
        const __bf16* hb = hbuf[1] + tid * S_H;
        float s = bd[0];
#pragma unroll
        for (int u = 0; u < U_; ++u) s = fmaf((float)hb[u], Wd[u], s);
        out[bb + tid] = sigmoidf_(s);
    }
}

// ---------------------------------------------------------------------------
extern "C" void kernel_launch(void* const* d_in, const int* in_sizes, int n_in,
                              void* d_out, int out_size, void* d_ws, size_t ws_size,
                              hipStream_t stream) {
    const int*   tokens = (const int*)  d_in[0];
    const float* emb    = (const float*)d_in[1];
    // d_in[2..4] = k0, r0, b0 : dead in the reference (cell0 state unused)
    const float* k1     = (const float*)d_in[5];
    const float* r1     = (const float*)d_in[6];
    const float* b1     = (const float*)d_in[7];
    const float* Wd     = (const float*)d_in[8];
    const float* bd     = (const float*)d_in[9];
    float*       out    = (float*)d_out;

    float* embk = (float*)d_ws;              // V_*G_ floats = 10.24 MB

    embk_kernel<<<((V_ + 63) / 64) * 2, 256, 0, stream>>>(emb, k1, b1, embk);
    lstm_kernel<<<B_ / 16, 256, 0, stream>>>(tokens, embk, r1, Wd, bd, out);
}